// Round 8
// baseline (763.539 us; speedup 1.0000x reference)
//
#include <hip/hip_runtime.h>
#include <hip/hip_bf16.h>
#include <stdint.h>

// WindowAttention: B_=256 windows, N=98 tokens, DIM=768, NH=24, HD=32.
// Round 8: GEMM epilogue writes de-interleaved Q[b][h][t][32], K[b][h][t][32],
// V[b][h][d][128] (transposed). Attention reads MFMA fragments DIRECTLY from
// global; LDS only for the P (C->A layout) transform, padded stride 136 to
// kill bank conflicts. GEMM stages A from fp32 x inline (no xb buffer).
// Inputs fp32, output fp32.

#define NTOK 98
#define MT 7
#define NPAD 112
#define DIMX 768
#define NHEAD 24
#define HDIM 32
#define NQKV 2304          // 3*DIM
#define BROWS 25088        // 256*98
#define PST 136            // P LDS row stride (shorts); 272B -> conflict-free
#define SCALE 0.17677669529663689f

typedef __attribute__((ext_vector_type(8))) short short8;
typedef __attribute__((ext_vector_type(4))) short short4v;
typedef __attribute__((ext_vector_type(4))) float floatx4;

__device__ __forceinline__ short f2b(float f) {
    __hip_bfloat16 h = __float2bfloat16(f);
    return __builtin_bit_cast(short, h);
}

__device__ __forceinline__ void gload_lds16(const void* g, void* l) {
    __builtin_amdgcn_global_load_lds(
        (const __attribute__((address_space(1))) void*)g,
        (__attribute__((address_space(3))) void*)l, 16, 0, 0);
}

// ---------------- fp32 -> bf16 bulk convert (for W only) ----------------
__global__ void convert_kernel(const float* __restrict__ src,
                               short* __restrict__ dst, int n4) {
    int i = blockIdx.x * 256 + threadIdx.x;
    int stride = gridDim.x * 256;
    for (; i < n4; i += stride) {
        float4 f = ((const float4*)src)[i];
        short4v s = { f2b(f.x), f2b(f.y), f2b(f.z), f2b(f.w) };
        ((short4v*)dst)[i] = s;
    }
}

// bias_pre[h][i][j] = rel_table[rel_index[i][j]][h]
__global__ void bias_gather_kernel(const float* __restrict__ rel_table,
                                   const int* __restrict__ rel_index,
                                   float* __restrict__ bias_pre) {
    int t = blockIdx.x * 256 + threadIdx.x;
    if (t >= NHEAD * NTOK * NTOK) return;
    int h  = t / (NTOK * NTOK);
    int ij = t % (NTOK * NTOK);
    bias_pre[t] = rel_table[(size_t)rel_index[ij] * NHEAD + h];
}

// ---------------- GEMM: (x @ W^T + b) -> de-interleaved Q/K/V --------------
// 128x128 tiles, BK=64, 256 thr (2x2 waves, each 4x4 16x16x32 MFMA tiles).
// A staged from fp32 x with inline convert; B via global_load_lds from wb.
__global__ void gemm_kernel(const float* __restrict__ x,
                            const short* __restrict__ wb,
                            const float* __restrict__ qkv_b,
                            short* __restrict__ Q,
                            short* __restrict__ K,
                            short* __restrict__ V) {
    __shared__ short At[128 * 64];
    __shared__ short Bt[128 * 64];
    const int tid  = threadIdx.x;
    const int lane = tid & 63;
    const int wv   = tid >> 6;
    const int wr   = wv >> 1, wc = wv & 1;
    const int l15  = lane & 15;
    const int l4   = lane >> 4;

    const int mtile = blockIdx.x / 18;
    const int ntile = blockIdx.x % 18;

    const float* aB = x + (size_t)(mtile * 128) * DIMX;
    const short* bB = wb + (size_t)(ntile * 128) * DIMX;
    const int lrow = lane >> 3;         // 0..7
    const int lcol = (lane & 7) * 8;    // 0..56

    floatx4 acc[4][4];
    #pragma unroll
    for (int m = 0; m < 4; ++m)
        #pragma unroll
        for (int n = 0; n < 4; ++n) acc[m][n] = (floatx4){0.f, 0.f, 0.f, 0.f};

    for (int kb = 0; kb < 12; ++kb) {
        // B: async global->LDS (bf16, pre-converted)
        #pragma unroll
        for (int j = 0; j < 4; ++j) {
            int r = wv * 32 + j * 8;
            gload_lds16(bB + (size_t)(r + lrow) * DIMX + kb * 64 + lcol, &Bt[r * 64]);
        }
        // A: fp32 load + convert + LDS store (overlaps with B in flight)
        #pragma unroll
        for (int i = 0; i < 8; ++i) {
            int idx = tid + i * 256;            // 2048 float4
            int row = idx >> 4, c4 = (idx & 15) * 4;
            float4 f = *(const float4*)(aB + (size_t)row * DIMX + kb * 64 + c4);
            short4v s = { f2b(f.x), f2b(f.y), f2b(f.z), f2b(f.w) };
            *(short4v*)(&At[row * 64 + c4]) = s;
        }
        __syncthreads();
        #pragma unroll
        for (int kh = 0; kh < 2; ++kh) {
            int k0 = kh * 32 + l4 * 8;
            short8 af[4], bfr[4];
            #pragma unroll
            for (int m = 0; m < 4; ++m)
                af[m] = *(const short8*)(&At[(wr * 64 + m * 16 + l15) * 64 + k0]);
            #pragma unroll
            for (int n = 0; n < 4; ++n)
                bfr[n] = *(const short8*)(&Bt[(wc * 64 + n * 16 + l15) * 64 + k0]);
            #pragma unroll
            for (int m = 0; m < 4; ++m)
                #pragma unroll
                for (int n = 0; n < 4; ++n)
                    acc[m][n] = __builtin_amdgcn_mfma_f32_16x16x32_bf16(
                        af[m], bfr[n], acc[m][n], 0, 0, 0);
        }
        __syncthreads();
    }

    // Epilogue: scatter to Q[b][h][t][32], K[b][h][t][32], V[b][h][d][128]
    #pragma unroll
    for (int n = 0; n < 4; ++n) {
        int col = ntile * 128 + wc * 64 + n * 16 + l15;   // 0..2303
        int h   = col / 96;
        int rem = col - h * 96;
        int d   = rem / 3;
        int s   = rem - d * 3;
        float bias = qkv_b[col];
        #pragma unroll
        for (int m = 0; m < 4; ++m) {
            int grow0 = mtile * 128 + wr * 64 + m * 16 + l4 * 4;
            #pragma unroll
            for (int r = 0; r < 4; ++r) {
                int grow = grow0 + r;
                int bb = grow / 98;
                int tt = grow - bb * 98;
                short val = f2b(acc[m][n][r] + bias);
                size_t slice = (size_t)(bb * NHEAD + h);
                if (s == 0)      Q[slice * NTOK * HDIM + tt * HDIM + d] = val;
                else if (s == 1) K[slice * NTOK * HDIM + tt * HDIM + d] = val;
                else             V[slice * HDIM * 128 + d * 128 + tt] = val;
            }
        }
    }
}

// ---------------- Attention per (window b, head h) ----------------
// LDS only for P (112 x PST). Q/K/V fragments read directly from global.
__global__ __launch_bounds__(256, 4) void attn_kernel3(
    const short* __restrict__ Q,
    const short* __restrict__ K,
    const short* __restrict__ V,
    const float* __restrict__ mask,
    const float* __restrict__ bias_pre,
    float* __restrict__ out) {
    __shared__ short P[NPAD * PST];   // 30464 B
    const int tid  = threadIdx.x;
    const int lane = tid & 63;
    const int wv   = tid >> 6;
    const int l15  = lane & 15;
    const int l4   = lane >> 4;
    const int b = blockIdx.x / NHEAD;
    const int h = blockIdx.x % NHEAD;

    const size_t slice = (size_t)(b * NHEAD + h);
    const short* Qs = Q + slice * NTOK * HDIM;
    const short* Ks = K + slice * NTOK * HDIM;
    const short* Vs = V + slice * HDIM * 128;

    int mt[2];
    mt[0] = wv;
    mt[1] = (wv + 4 < MT) ? (wv + 4) : wv;   // wave3 duplicates tile 3 (benign)

    // zero P cols 112..127 (cols 0..111 written by softmax; >=128 never read)
    for (int t = tid; t < NPAD * 16; t += 256) {
        int row = t >> 4, c = 112 + (t & 15);
        P[row * PST + c] = 0;
    }

    // Phase 2: S = q @ k^T (K=32, one MFMA step), fragments from global.
    // m-tile 6 rows 98..111 read past the slice: finite garbage, rows masked.
    floatx4 sacc[2][7];
    #pragma unroll
    for (int i = 0; i < 2; ++i)
        #pragma unroll
        for (int j = 0; j < 7; ++j) sacc[i][j] = (floatx4){0.f, 0.f, 0.f, 0.f};
    {
        short8 aq[2];
        #pragma unroll
        for (int im = 0; im < 2; ++im)
            aq[im] = *(const short8*)(Qs + (size_t)(mt[im] * 16 + l15) * HDIM + l4 * 8);
        #pragma unroll
        for (int nt = 0; nt < 7; ++nt) {
            short8 bk = *(const short8*)(Ks + (size_t)(nt * 16 + l15) * HDIM + l4 * 8);
            #pragma unroll
            for (int im = 0; im < 2; ++im)
                sacc[im][nt] = __builtin_amdgcn_mfma_f32_16x16x32_bf16(
                    aq[im], bk, sacc[im][nt], 0, 0, 0);
        }
    }

    const float* biash = bias_pre + (size_t)h * NTOK * NTOK;
    const size_t moff = (size_t)(b & 63) * NTOK * NTOK;

    #pragma unroll
    for (int im = 0; im < 2; ++im) {
        #pragma unroll
        for (int r = 0; r < 4; ++r) {
            int row = mt[im] * 16 + l4 * 4 + r;
            bool vrow = row < NTOK;
            float v[7];
            #pragma unroll
            for (int nt = 0; nt < 7; ++nt) {
                int j = nt * 16 + l15;
                bool vj = vrow && (j < NTOK);
                float bm = 0.f;
                if (vj) bm = biash[row * NTOK + j] + mask[moff + row * NTOK + j];
                v[nt] = vj ? sacc[im][nt][r] * SCALE + bm : -1e30f;
            }
            float mx = v[0];
            #pragma unroll
            for (int nt = 1; nt < 7; ++nt) mx = fmaxf(mx, v[nt]);
            #pragma unroll
            for (int off = 1; off < 16; off <<= 1) mx = fmaxf(mx, __shfl_xor(mx, off));
            float s = 0.f;
            #pragma unroll
            for (int nt = 0; nt < 7; ++nt) {
                float e = (v[nt] > -1e29f) ? __expf(v[nt] - mx) : 0.f;
                v[nt] = e;
                s += e;
            }
            #pragma unroll
            for (int off = 1; off < 16; off <<= 1) s += __shfl_xor(s, off);
            float inv = vrow ? 1.f / s : 0.f;   // rows >= 98 -> zero probs
            #pragma unroll
            for (int nt = 0; nt < 7; ++nt)
                P[row * PST + nt * 16 + l15] = f2b(v[nt] * inv);
        }
    }
    __syncthreads();

    // Phase 3: O = P(98x128pad) @ V(128x32); V fragments from global.
    // V pad cols 98..127 are ws poison (finite bf16) * P==0 -> 0.
    floatx4 oacc[2][2];
    #pragma unroll
    for (int i = 0; i < 2; ++i)
        #pragma unroll
        for (int j = 0; j < 2; ++j) oacc[i][j] = (floatx4){0.f, 0.f, 0.f, 0.f};

    #pragma unroll
    for (int kt = 0; kt < 4; ++kt) {
        int kk = kt * 32 + l4 * 8;
        short8 ap[2];
        #pragma unroll
        for (int im = 0; im < 2; ++im)
            ap[im] = *(const short8*)(&P[(mt[im] * 16 + l15) * PST + kk]);
        #pragma unroll
        for (int nt = 0; nt < 2; ++nt) {
            short8 bv = *(const short8*)(Vs + (size_t)(nt * 16 + l15) * 128 + kk);
            #pragma unroll
            for (int im = 0; im < 2; ++im)
                oacc[im][nt] = __builtin_amdgcn_mfma_f32_16x16x32_bf16(
                    ap[im], bv, oacc[im][nt], 0, 0, 0);
        }
    }

    float* ob = out + (size_t)b * NTOK * DIMX + h * HDIM;
    #pragma unroll
    for (int im = 0; im < 2; ++im)
        #pragma unroll
        for (int nt = 0; nt < 2; ++nt) {
            int dd = nt * 16 + l15;
            #pragma unroll
            for (int r = 0; r < 4; ++r) {
                int tok = mt[im] * 16 + l4 * 4 + r;
                if (tok < NTOK)
                    ob[(size_t)tok * DIMX + dd] = oacc[im][nt][r];
            }
        }
}

// ---------------- Fallback: round-6 fused kernel (fp32 in, fp32 out) -------
struct __align__(16) SMemF {
    union {
        struct {
            short xt[NPAD * 64];
            short wt[96 * 64];
        } p1;
        short P[NPAD * 128];
    } u;
    short q[NPAD * HDIM];
    short k[NPAD * HDIM];
    short vt[HDIM * 128];
};

__global__ __launch_bounds__(256, 3) void attn_fused(
    const float* __restrict__ x,
    const float* __restrict__ mask,
    const float* __restrict__ qkv_w,
    const float* __restrict__ qkv_b,
    const float* __restrict__ bias_pre,
    const float* __restrict__ rel_table,
    const int* __restrict__ rel_index,
    float* __restrict__ out) {
    __shared__ SMemF sm;
    const int tid  = threadIdx.x;
    const int lane = tid & 63;
    const int wv   = tid >> 6;
    const int l15  = lane & 15;
    const int l4   = lane >> 4;
    const int b = blockIdx.x / NHEAD;
    const int h = blockIdx.x % NHEAD;
    const float* xp = x + (size_t)b * NTOK * DIMX;
    const float* wp = qkv_w + (size_t)h * 96 * DIMX;
    int mt[2];
    mt[0] = wv;
    mt[1] = (wv + 4 < MT) ? (wv + 4) : wv;

    floatx4 acc[2][6];
    #pragma unroll
    for (int i = 0; i < 2; ++i)
        #pragma unroll
        for (int j = 0; j < 6; ++j) acc[i][j] = (floatx4){0.f, 0.f, 0.f, 0.f};

    for (int kb = 0; kb < 12; ++kb) {
        for (int t = tid; t < NTOK * 16; t += 256) {
            int row = t >> 4, c = t & 15;
            float4 f = *(const float4*)(xp + (size_t)row * DIMX + kb * 64 + c * 4);
            short4v s = { f2b(f.x), f2b(f.y), f2b(f.z), f2b(f.w) };
            *(short4v*)(&sm.u.p1.xt[row * 64 + c * 4]) = s;
        }
        for (int t = tid; t < 96 * 16; t += 256) {
            int row = t >> 4, c = t & 15;
            float4 f = *(const float4*)(wp + (size_t)row * DIMX + kb * 64 + c * 4);
            short4v s = { f2b(f.x), f2b(f.y), f2b(f.z), f2b(f.w) };
            *(short4v*)(&sm.u.p1.wt[row * 64 + c * 4]) = s;
        }
        if (tid < 14 * 8) {
            int row = 98 + (tid >> 3), c = tid & 7;
            uint4 z = {0u, 0u, 0u, 0u};
            *(uint4*)(&sm.u.p1.xt[row * 64 + c * 8]) = z;
        }
        __syncthreads();
        #pragma unroll
        for (int ks = 0; ks < 2; ++ks) {
            int k0 = ks * 32 + l4 * 8;
            short8 aM[2];
            #pragma unroll
            for (int im = 0; im < 2; ++im)
                aM[im] = *(const short8*)(&sm.u.p1.xt[(mt[im] * 16 + l15) * 64 + k0]);
            #pragma unroll
            for (int nt = 0; nt < 6; ++nt) {
                short8 bN = *(const short8*)(&sm.u.p1.wt[(nt * 16 + l15) * 64 + k0]);
                #pragma unroll
                for (int im = 0; im < 2; ++im)
                    acc[im][nt] = __builtin_amdgcn_mfma_f32_16x16x32_bf16(
                        aM[im], bN, acc[im][nt], 0, 0, 0);
            }
        }
        __syncthreads();
    }

    #pragma unroll
    for (int im = 0; im < 2; ++im)
        #pragma unroll
        for (int nt = 0; nt < 6; ++nt) {
            int col = nt * 16 + l15;
            int d = col / 3, s = col % 3;
            float bias = qkv_b[h * 96 + col];
            #pragma unroll
            for (int r = 0; r < 4; ++r) {
                int tok = mt[im] * 16 + l4 * 4 + r;
                short val = f2b(acc[im][nt][r] + bias);
                if (s == 0)      sm.q[tok * HDIM + d] = val;
                else if (s == 1) sm.k[tok * HDIM + d] = val;
                else             sm.vt[d * 128 + tok] = val;
            }
        }
    __syncthreads();
    for (int t = tid; t < HDIM * 30; t += 256) {
        int d = t / 30, c = 98 + t % 30;
        sm.vt[d * 128 + c] = 0;
    }
    for (int t = tid; t < NPAD * 16; t += 256) {
        int row = t >> 4, c = 112 + (t & 15);
        sm.u.P[row * 128 + c] = 0;
    }

    floatx4 sacc[2][7];
    #pragma unroll
    for (int i = 0; i < 2; ++i)
        #pragma unroll
        for (int j = 0; j < 7; ++j) sacc[i][j] = (floatx4){0.f, 0.f, 0.f, 0.f};
    {
        int k0 = l4 * 8;
        short8 aq[2];
        #pragma unroll
        for (int im = 0; im < 2; ++im)
            aq[im] = *(const short8*)(&sm.q[(mt[im] * 16 + l15) * HDIM + k0]);
        #pragma unroll
        for (int nt = 0; nt < 7; ++nt) {
            short8 bk = *(const short8*)(&sm.k[(nt * 16 + l15) * HDIM + k0]);
            #pragma unroll
            for (int im = 0; im < 2; ++im)
                sacc[im][nt] = __builtin_amdgcn_mfma_f32_16x16x32_bf16(
                    aq[im], bk, sacc[im][nt], 0, 0, 0);
        }
    }

    const float* biash = bias_pre ? (bias_pre + (size_t)h * NTOK * NTOK) : nullptr;
    const size_t moff = (size_t)(b & 63) * NTOK * NTOK;

    #pragma unroll
    for (int im = 0; im < 2; ++im)
        #pragma unroll
        for (int r = 0; r < 4; ++r) {
            int row = mt[im] * 16 + l4 * 4 + r;
            bool vrow = row < NTOK;
            float v[7];
            #pragma unroll
            for (int nt = 0; nt < 7; ++nt) {
                int j = nt * 16 + l15;
                bool vj = vrow && (j < NTOK);
                float bm = 0.f;
                if (vj) {
                    float bias = biash ? biash[row * NTOK + j]
                        : rel_table[(size_t)rel_index[row * NTOK + j] * NHEAD + h];
                    bm = bias + mask[moff + row * NTOK + j];
                }
                v[nt] = vj ? sacc[im][nt][r] * SCALE + bm : -1e30f;
            }
            float mx = v[0];
            #pragma unroll
            for (int nt = 1; nt < 7; ++nt) mx = fmaxf(mx, v[nt]);
            #pragma unroll
            for (int off = 1; off < 16; off <<= 1) mx = fmaxf(mx, __shfl_xor(mx, off));
            float s = 0.f;
            #pragma unroll
            for (int nt = 0; nt < 7; ++nt) {
                float e = (v[nt] > -1e29f) ? __expf(v[nt] - mx) : 0.f;
                v[nt] = e;
                s += e;
            }
            #pragma unroll
            for (int off = 1; off < 16; off <<= 1) s += __shfl_xor(s, off);
            float inv = vrow ? 1.f / s : 0.f;
            #pragma unroll
            for (int nt = 0; nt < 7; ++nt)
                sm.u.P[row * 128 + nt * 16 + l15] = f2b(v[nt] * inv);
        }
    __syncthreads();

    floatx4 oacc[2][2];
    #pragma unroll
    for (int i = 0; i < 2; ++i)
        #pragma unroll
        for (int j = 0; j < 2; ++j) oacc[i][j] = (floatx4){0.f, 0.f, 0.f, 0.f};
    #pragma unroll
    for (int kt = 0; kt < 4; ++kt) {
        int kk = kt * 32 + l4 * 8;
        short8 ap[2];
        #pragma unroll
        for (int im = 0; im < 2; ++im)
            ap[im] = *(const short8*)(&sm.u.P[(mt[im] * 16 + l15) * 128 + kk]);
        #pragma unroll
        for (int nt = 0; nt < 2; ++nt) {
            short8 bv = *(const short8*)(&sm.vt[(nt * 16 + l15) * 128 + kk]);
            #pragma unroll
            for (int im = 0; im < 2; ++im)
                oacc[im][nt] = __builtin_amdgcn_mfma_f32_16x16x32_bf16(
                    ap[im], bv, oacc[im][nt], 0, 0, 0);
        }
    }
    float* ob = out + (size_t)b * NTOK * DIMX + h * HDIM;
    #pragma unroll
    for (int im = 0; im < 2; ++im)
        #pragma unroll
        for (int nt = 0; nt < 2; ++nt) {
            int dd = nt * 16 + l15;
            #pragma unroll
            for (int r = 0; r < 4; ++r) {
                int tok = mt[im] * 16 + l4 * 4 + r;
                if (tok < NTOK)
                    ob[(size_t)tok * DIMX + dd] = oacc[im][nt][r];
            }
        }
}

extern "C" void kernel_launch(void* const* d_in, const int* in_sizes, int n_in,
                              void* d_out, int out_size, void* d_ws, size_t ws_size,
                              hipStream_t stream) {
    const float* x = (const float*)d_in[0];
    const float* mask = (const float*)d_in[1];
    const float* qkv_w = (const float*)d_in[2];
    const float* qkv_b = (const float*)d_in[3];
    const float* rel_table = (const float*)d_in[4];
    const int* rel_index = (const int*)d_in[5];
    for (int i = 0; i < n_in; ++i) {
        switch (in_sizes[i]) {
            case 256 * NTOK * DIMX:  x         = (const float*)d_in[i]; break;
            case 64 * NTOK * NTOK:   mask      = (const float*)d_in[i]; break;
            case 3 * DIMX * DIMX:    qkv_w     = (const float*)d_in[i]; break;
            case 3 * DIMX:           qkv_b     = (const float*)d_in[i]; break;
            case 507 * NHEAD:        rel_table = (const float*)d_in[i]; break;
            case NTOK * NTOK:        rel_index = (const int*)d_in[i]; break;
            default: break;
        }
    }
    float* out = (float*)d_out;

    const size_t bias_bytes = (size_t)NHEAD * NTOK * NTOK * 4;        //  3,687,936
    const size_t wb_bytes   = (size_t)NQKV * DIMX * 2;                //  3,538,944
    const size_t q_bytes    = (size_t)256 * NHEAD * NTOK * HDIM * 2;  // 38,535,168
    const size_t v_bytes    = (size_t)256 * NHEAD * HDIM * 128 * 2;   // 50,331,648
    const size_t total = bias_bytes + wb_bytes + 2 * q_bytes + v_bytes; // 134,628,864

    if (ws_size >= total) {
        char* p = (char*)d_ws;
        float* bias_pre = (float*)p;                 p += bias_bytes;
        short* wb = (short*)p;                       p += wb_bytes;
        short* Qb = (short*)p;                       p += q_bytes;
        short* Kb = (short*)p;                       p += q_bytes;
        short* Vb = (short*)p;

        int nw4 = NQKV * DIMX / 4;   // 442368
        convert_kernel<<<(nw4 + 255) / 256, 256, 0, stream>>>(qkv_w, wb, nw4);
        int nb = NHEAD * NTOK * NTOK;
        bias_gather_kernel<<<(nb + 255) / 256, 256, 0, stream>>>(rel_table, rel_index, bias_pre);
        gemm_kernel<<<196 * 18, 256, 0, stream>>>(x, wb, qkv_b, Qb, Kb, Vb);
        attn_kernel3<<<256 * NHEAD, 256, 0, stream>>>(Qb, Kb, Vb, mask, bias_pre, out);
    } else {
        float* bias_pre = (ws_size >= bias_bytes) ? (float*)d_ws : nullptr;
        if (bias_pre) {
            int nb = NHEAD * NTOK * NTOK;
            bias_gather_kernel<<<(nb + 255) / 256, 256, 0, stream>>>(rel_table, rel_index, bias_pre);
        }
        attn_fused<<<256 * NHEAD, 256, 0, stream>>>(x, mask, qkv_w, qkv_b,
                                                    bias_pre, rel_table, rel_index, out);
    }
}